// Round 1
// baseline (248.708 us; speedup 1.0000x reference)
//
#include <hip/hip_runtime.h>

#define N_INPUTS 16384
#define N_DET    65536
#define K        32
#define B        32

// ---------------------------------------------------------------------------
// Pass 1: occurrence histogram over detector table (batch-independent).
// 2M valid slot-occurrences -> occ[id]++ . Grid-stride-free: exact-size grid.
// ---------------------------------------------------------------------------
__global__ __launch_bounds__(256) void occ_hist(const int* __restrict__ det,
                                                int* __restrict__ occ) {
    int i = blockIdx.x * 256 + threadIdx.x;            // over N_DET*K/4 int4s
    const int4* d4 = (const int4*)det;
    int4 v = d4[i];
    if (v.x >= 0) atomicAdd(&occ[v.x], 1);
    if (v.y >= 0) atomicAdd(&occ[v.y], 1);
    if (v.z >= 0) atomicAdd(&occ[v.z], 1);
    if (v.w >= 0) atomicAdd(&occ[v.w], 1);
}

// ---------------------------------------------------------------------------
// Pass 2: per (batch, detector) argmax winner -> win[b][winner_id]++ .
// One block = one batch row (staged in 64KB LDS) x 2048 detectors.
// grid = (N_DET/2048, B). Strict '>' keeps the FIRST max slot, matching
// jnp.argmax tie-break (also correct for duplicate ids: later dup loses).
// ---------------------------------------------------------------------------
__global__ __launch_bounds__(256) void winners(const float* __restrict__ x,
                                               const int* __restrict__ det,
                                               int* __restrict__ win) {
    __shared__ float xs[N_INPUTS];                     // 64 KiB
    const int b = blockIdx.y;
    const float4* x4  = (const float4*)(x + (size_t)b * N_INPUTS);
    float4*       xs4 = (float4*)xs;
#pragma unroll
    for (int i = 0; i < N_INPUTS / 4 / 256; ++i)       // 16 coalesced float4 each
        xs4[threadIdx.x + i * 256] = x4[threadIdx.x + i * 256];
    __syncthreads();

    const int   dbase = blockIdx.x * 2048;
    int*        winb  = win + (size_t)b * N_INPUTS;
    const int4* det4  = (const int4*)det;

    for (int j = 0; j < 8; ++j) {
        int d = dbase + j * 256 + threadIdx.x;
        float best = -INFINITY;
        int bestId = -1;
#pragma unroll
        for (int q = 0; q < 8; ++q) {
            int4 id = det4[d * 8 + q];                 // 128B row via 8x int4, L1-friendly
            if (id.x >= 0) { float v = xs[id.x]; if (v > best) { best = v; bestId = id.x; } }
            if (id.y >= 0) { float v = xs[id.y]; if (v > best) { best = v; bestId = id.y; } }
            if (id.z >= 0) { float v = xs[id.z]; if (v > best) { best = v; bestId = id.z; } }
            if (id.w >= 0) { float v = xs[id.w]; if (v > best) { best = v; bestId = id.w; } }
        }
        if (bestId >= 0) atomicAdd(&winb[bestId], 1);  // exactly one win per (b,d)
    }
}

// ---------------------------------------------------------------------------
// Pass 3: out[b][i] = (win[b][i] == occ[i]) ? 1.0 : 0.0, in place over d_out
// (win counts were accumulated as int32 in the same buffer).
// ---------------------------------------------------------------------------
__global__ __launch_bounds__(256) void finalize(int* __restrict__ wo,
                                                const int* __restrict__ occ) {
    int i = blockIdx.x * 256 + threadIdx.x;            // over B*N_INPUTS/4 int4s
    int4 w = ((const int4*)wo)[i];
    int4 o = ((const int4*)occ)[i & (N_INPUTS / 4 - 1)];
    float4 r;
    r.x = (w.x == o.x) ? 1.0f : 0.0f;
    r.y = (w.y == o.y) ? 1.0f : 0.0f;
    r.z = (w.z == o.z) ? 1.0f : 0.0f;
    r.w = (w.w == o.w) ? 1.0f : 0.0f;
    ((float4*)wo)[i] = r;
}

extern "C" void kernel_launch(void* const* d_in, const int* in_sizes, int n_in,
                              void* d_out, int out_size, void* d_ws, size_t ws_size,
                              hipStream_t stream) {
    const float* x   = (const float*)d_in[0];          // [B, N_INPUTS] f32
    const int*   det = (const int*)d_in[1];            // [N_DET, K] i32
    int*         win = (int*)d_out;                    // reused: int counts then float out
    int*         occ = (int*)d_ws;                     // 64 KiB scratch

    hipMemsetAsync(d_out, 0, (size_t)B * N_INPUTS * sizeof(int), stream);
    hipMemsetAsync(d_ws, 0, (size_t)N_INPUTS * sizeof(int), stream);

    occ_hist<<<N_DET * K / 4 / 256, 256, 0, stream>>>(det, occ);

    dim3 grid(N_DET / 2048, B);
    winners<<<grid, 256, 0, stream>>>(x, det, win);

    finalize<<<B * N_INPUTS / 4 / 256, 256, 0, stream>>>(win, occ);
}

// Round 2
// 104.266 us; speedup vs baseline: 2.3853x; 2.3853x over previous
//
#include <hip/hip_runtime.h>

#define N_INPUTS 16384
#define N_DET    65536
#define KD       32
#define BATCH    32
#define SLICES   8                         // det slices; slice s -> XCD s via bid%8
#define DPB      (N_DET / SLICES)          // 8192 detectors per block
#define THREADS  1024                      // 16 waves/block, 1 block/CU (128 KB LDS)

// ---------------------------------------------------------------------------
// Main kernel: one block = (one batch row staged in LDS) x (one detector
// slice). For each detector: gather 32 member activations from LDS, find the
// argmax slot (strict '>' scan = first-max, matching jnp.argmax; duplicate
// ids handled because losers are identified by SLOT, not id), then flag every
// non-winner member id in an LDS flag array with a plain store (idempotent
// '=1' -> no atomics anywhere). Flags are packed to a 16384-bit mask via
// __ballot and written as a 2 KB per-block partial.
// ---------------------------------------------------------------------------
__global__ __launch_bounds__(THREADS) void inhibit(const float* __restrict__ x,
                                                   const int* __restrict__ det,
                                                   unsigned long long* __restrict__ pm) {
    __shared__ float    xs[N_INPUTS];      // 64 KB: full x row
    __shared__ unsigned inh[N_INPUTS];     // 64 KB: loser flags (u32 -> conflict-free pack)

    const int slice = blockIdx.x & (SLICES - 1);   // bid%8 -> same slice on same XCD
    const int batch = blockIdx.x >> 3;
    const int tid   = threadIdx.x;

    // zero flags: 16384 words / 1024 threads = 4x uint4
    uint4* inh4 = (uint4*)inh;
#pragma unroll
    for (int k = 0; k < N_INPUTS / 4 / THREADS; ++k)
        inh4[tid + k * THREADS] = make_uint4(0u, 0u, 0u, 0u);

    // stage x row: 4x float4, coalesced
    const float4* x4  = (const float4*)(x + (size_t)batch * N_INPUTS);
    float4*       xs4 = (float4*)xs;
#pragma unroll
    for (int k = 0; k < N_INPUTS / 4 / THREADS; ++k)
        xs4[tid + k * THREADS] = x4[tid + k * THREADS];
    __syncthreads();

    const int4* det4 = (const int4*)det;
    for (int j = 0; j < DPB / THREADS; ++j) {      // 8 detectors per thread
        const int   d    = slice * DPB + j * THREADS + tid;
        const int4* drow = det4 + (size_t)d * 8;   // 128 B = one cache line per row
        int ids[KD];
#pragma unroll
        for (int q = 0; q < 8; ++q) {
            int4 r = drow[q];
            ids[q * 4 + 0] = r.x; ids[q * 4 + 1] = r.y;
            ids[q * 4 + 2] = r.z; ids[q * 4 + 3] = r.w;
        }
        // unconditional gathers (guard folded to select) -> compiler can batch
        // all 32 ds_reads ahead of the compare chain
        float best = -INFINITY;
        int   bs   = -1;
#pragma unroll
        for (int s = 0; s < KD; ++s) {
            int   id = ids[s];
            float v  = xs[id < 0 ? 0 : id];
            v = (id >= 0) ? v : -INFINITY;
            if (v > best) { best = v; bs = s; }
        }
#pragma unroll
        for (int s = 0; s < KD; ++s) {
            int id = ids[s];
            if (s != bs && id >= 0) inh[id] = 1u;  // plain store, race-safe
        }
    }
    __syncthreads();

    // pack 16384 flags -> 256 u64 mask words via ballot (16 per wave)
    const int lane = tid & 63;
    const int wv   = tid >> 6;
    unsigned long long* pmb =
        pm + ((size_t)(batch * SLICES + slice)) * (N_INPUTS / 64) + wv * 16;
#pragma unroll
    for (int i = 0; i < 16; ++i) {
        unsigned v = inh[wv * 1024 + i * 64 + lane];
        unsigned long long m = __ballot(v != 0u);
        if (lane == 0) pmb[i] = m;
    }
}

// ---------------------------------------------------------------------------
// Finalize: out[b][i] = 1.0 iff bit i clear in OR of the batch's 8 slice masks.
// ---------------------------------------------------------------------------
__global__ __launch_bounds__(256) void finalize(const unsigned* __restrict__ pm,
                                                float* __restrict__ out) {
    const int gid = blockIdx.x * 256 + threadIdx.x;   // 0 .. B*N_INPUTS-1
    const int b   = gid >> 14;
    const int i   = gid & (N_INPUTS - 1);
    unsigned acc = 0;
#pragma unroll
    for (int s = 0; s < SLICES; ++s)
        acc |= pm[((b * SLICES + s) << 9) + (i >> 5)]; // 512 u32 words per partial
    out[gid] = ((acc >> (i & 31)) & 1u) ? 0.0f : 1.0f;
}

extern "C" void kernel_launch(void* const* d_in, const int* in_sizes, int n_in,
                              void* d_out, int out_size, void* d_ws, size_t ws_size,
                              hipStream_t stream) {
    const float* x   = (const float*)d_in[0];              // [B, N_INPUTS] f32
    const int*   det = (const int*)d_in[1];                // [N_DET, K] i32
    unsigned long long* pm = (unsigned long long*)d_ws;    // 512 KB partial masks

    inhibit<<<BATCH * SLICES, THREADS, 0, stream>>>(x, det, pm);
    finalize<<<BATCH * N_INPUTS / 256, 256, 0, stream>>>((const unsigned*)pm,
                                                         (float*)d_out);
}

// Round 3
// 93.057 us; speedup vs baseline: 2.6726x; 1.1205x over previous
//
#include <hip/hip_runtime.h>

#define N_INPUTS 16384
#define N_DET    65536
#define KD       32
#define BATCH    32
#define SLICES   16                        // det slices; slice s -> XCD s%8
#define DPB      (N_DET / SLICES)          // 4096 detectors per block
#define THREADS  1024                      // 16 waves, 1 block/CU (160 KB LDS)

// ---------------------------------------------------------------------------
// One block = (2 batch rows interleaved in LDS as float2) x (one detector
// slice). Per detector: one ds_read_b64 per member id yields BOTH batches'
// activations; two independent first-max argmax scans (strict '>', matching
// jnp.argmax tie-break; duplicate ids correct because losers are slots).
// Flag stores: a slot that loses in both batches (the ~94% common case) is
// one 2-byte store of 0x0101 into a ushort flag word; the only slots that
// lose in exactly one batch are the two winner slots (when they differ),
// flagged once per detector with byte stores. No atomics anywhere (flags are
// idempotent '=1'; byte-enables make mixed byte/short stores race-safe).
// ---------------------------------------------------------------------------
__global__ __launch_bounds__(THREADS) void inhibit(const float* __restrict__ x,
                                                   const int* __restrict__ det,
                                                   unsigned long long* __restrict__ pm) {
    __shared__ float2         xs[N_INPUTS];    // 128 KB: [id] -> (x_b0, x_b1)
    __shared__ unsigned short inh[N_INPUTS];   // 32 KB: byte0=b0 loser, byte1=b1 loser

    const int slice = blockIdx.x;              // 16 values; same slice -> same XCD
    const int pair  = blockIdx.y;              // batch pair (2*pair, 2*pair+1)
    const int tid   = threadIdx.x;

    // zero flags: 32 KB = 2048 uint4 / 1024 threads
    uint4* z4 = (uint4*)inh;
#pragma unroll
    for (int k = 0; k < N_INPUTS * 2 / 16 / THREADS; ++k)
        z4[tid + k * THREADS] = make_uint4(0u, 0u, 0u, 0u);

    // stage both rows interleaved: xs[i] = (x[b0][i], x[b1][i])
    const float4* x0 = (const float4*)(x + (size_t)(2 * pair) * N_INPUTS);
    const float4* x1 = (const float4*)(x + (size_t)(2 * pair + 1) * N_INPUTS);
    float4* xs4 = (float4*)xs;
#pragma unroll
    for (int k = 0; k < N_INPUTS / 4 / THREADS; ++k) {
        int t = tid + k * THREADS;
        float4 a = x0[t], b = x1[t];
        xs4[2 * t + 0] = make_float4(a.x, b.x, a.y, b.y);
        xs4[2 * t + 1] = make_float4(a.z, b.z, a.w, b.w);
    }
    __syncthreads();

    const int4* det4 = (const int4*)det;
    for (int j = 0; j < DPB / THREADS; ++j) {  // 4 detectors per thread
        const int   d    = slice * DPB + j * THREADS + tid;
        const int4* drow = det4 + (size_t)d * 8;
        int ids[KD];
#pragma unroll
        for (int q = 0; q < 8; ++q) {
            int4 r = drow[q];
            ids[q * 4 + 0] = r.x; ids[q * 4 + 1] = r.y;
            ids[q * 4 + 2] = r.z; ids[q * 4 + 3] = r.w;
        }
        float b0 = -INFINITY, b1 = -INFINITY;
        int   s0 = -1, s1 = -1, w0 = -1, w1 = -1;
#pragma unroll
        for (int s = 0; s < KD; ++s) {
            int    id = ids[s];
            float2 v  = xs[id & (N_INPUTS - 1)];   // -1 masked; gated below
            bool   ok = id >= 0;
            float  vx = ok ? v.x : -INFINITY;
            float  vy = ok ? v.y : -INFINITY;
            if (vx > b0) { b0 = vx; s0 = s; w0 = id; }
            if (vy > b1) { b1 = vy; s1 = s; w1 = id; }
        }
#pragma unroll
        for (int s = 0; s < KD; ++s) {
            int id = ids[s];
            if (id >= 0 && s != s0 && s != s1)
                inh[id] = 0x0101;                  // loses in both batches
        }
        if (s0 != s1) {                            // winner slots cross-lose
            if (w0 >= 0) ((unsigned char*)inh)[2 * w0 + 1] = 1;  // b0 winner loses in b1
            if (w1 >= 0) ((unsigned char*)inh)[2 * w1 + 0] = 1;  // b1 winner loses in b0
        }
    }
    __syncthreads();

    // pack flags -> two 16384-bit masks via ballot (16 u64 words per wave each)
    const int lane = tid & 63;
    const int wv   = tid >> 6;
    unsigned long long* pm0 = pm + ((size_t)(2 * pair) * SLICES + slice) * (N_INPUTS / 64);
    unsigned long long* pm1 = pm + ((size_t)(2 * pair + 1) * SLICES + slice) * (N_INPUTS / 64);
#pragma unroll
    for (int k = 0; k < 16; ++k) {
        unsigned v = inh[wv * 1024 + k * 64 + lane];
        unsigned long long m0 = __ballot((v & 0x00FFu) != 0u);
        unsigned long long m1 = __ballot((v & 0xFF00u) != 0u);
        if (lane == 0) { pm0[wv * 16 + k] = m0; pm1[wv * 16 + k] = m1; }
    }
}

// ---------------------------------------------------------------------------
// out[b][i] = 1.0 iff bit i clear in OR of the batch's 16 slice masks.
// ---------------------------------------------------------------------------
__global__ __launch_bounds__(256) void finalize(const unsigned* __restrict__ pm,
                                                float* __restrict__ out) {
    const int gid = blockIdx.x * 256 + threadIdx.x;   // 0 .. B*N_INPUTS-1
    const int b   = gid >> 14;
    const int i   = gid & (N_INPUTS - 1);
    unsigned acc = 0;
#pragma unroll
    for (int s = 0; s < SLICES; ++s)
        acc |= pm[((b * SLICES + s) << 9) + (i >> 5)]; // 512 u32 per partial
    out[gid] = ((acc >> (i & 31)) & 1u) ? 0.0f : 1.0f;
}

extern "C" void kernel_launch(void* const* d_in, const int* in_sizes, int n_in,
                              void* d_out, int out_size, void* d_ws, size_t ws_size,
                              hipStream_t stream) {
    const float* x   = (const float*)d_in[0];              // [B, N_INPUTS] f32
    const int*   det = (const int*)d_in[1];                // [N_DET, K] i32
    unsigned long long* pm = (unsigned long long*)d_ws;    // 1 MB partial masks

    dim3 grid(SLICES, BATCH / 2);
    inhibit<<<grid, THREADS, 0, stream>>>(x, det, pm);
    finalize<<<BATCH * N_INPUTS / 256, 256, 0, stream>>>((const unsigned*)pm,
                                                         (float*)d_out);
}